// Round 11
// baseline (516.137 us; speedup 1.0000x reference)
//
#include <hip/hip_runtime.h>
#include <hip/hip_bf16.h>

#define BB 8
#define NN 2048
#define MM 2048
#define FF 64
#define INF __builtin_inff()

// ---- pipelined-DP geometry (skew-2) ----
// 8 bands of 256 rows per batch; one 64-lane WG per band; lane l owns rows
// 4l..4l+3. Tick T: lane l processes pair p = T - 2l (cols 2p, 2p+1).
// Skew-2 means the neighbor (lane l-1) computed pair p at tick T-2, so the
// cross-lane shfl is issued one tick early and its DS latency is off the
// critical chain (r10 post-mortem: the skew-1 shfl was ON the chain).
// Stripe t (1KB): lane l's 16B = rows 4l..4l+3 of cols 2(t-2l), 2(t-2l)+1.
#define STRIPES 1152                 // 1024 pairs + 126 skew + pad
#define BANDBYTES (STRIPES * 1024)
#define NBANDS 8
#define DIST_BYTES ((size_t)BB * NBANDS * BANDBYTES)
#define RING_SLOTS 1152              // float2 per producer tick
#define RING_BYTES ((size_t)BB * NBANDS * RING_SLOTS * 8)

typedef __hip_bfloat16 bf16;
typedef float f32x2 __attribute__((ext_vector_type(2)));

__device__ __forceinline__ unsigned pk_bf16x2(float a, float b) {
  union { __hip_bfloat162 h; unsigned u; } cv;
  cv.h.x = __float2bfloat16(a);
  cv.h.y = __float2bfloat16(b);
  return cv.u;
}

// ---------------- row norms ----------------
__global__ void norms_k(const float* __restrict__ a, float* __restrict__ o, int rows) {
  int r = blockIdx.x * 256 + threadIdx.x;
  if (r >= rows) return;
  const float4* p = (const float4*)(a + (size_t)r * FF);
  float s = 0.f;
#pragma unroll
  for (int q = 0; q < FF / 4; ++q) {
    float4 v = p[q];
    s = fmaf(v.x, v.x, fmaf(v.y, v.y, fmaf(v.z, v.z, fmaf(v.w, v.w, s))));
  }
  o[r] = s;
}

// ---------------- fill dist with 0x7F7F (bf16 = 3.39e38, INF-like, add-safe)
__global__ void fill_k(uint4* __restrict__ p, int n4) {
  int i = blockIdx.x * 256 + threadIdx.x;
  const int stride = gridDim.x * 256;
  const uint4 v = make_uint4(0x7F7F7F7Fu, 0x7F7F7F7Fu, 0x7F7F7F7Fu, 0x7F7F7F7Fu);
  for (; i < n4; i += stride) p[i] = v;
}

// ---------------- dist tile kernel (r9-verified; stripe index now skew-2) ----
__global__ __launch_bounds__(256) void dist_k(const float* __restrict__ X,
                                              const float* __restrict__ Y,
                                              const float* __restrict__ x2,
                                              const float* __restrict__ y2,
                                              char* __restrict__ dist) {
  __shared__ float xs[64][68];
  __shared__ float ysT[64][68];
  const int b = blockIdx.z, i0 = blockIdx.y * 64, j0 = blockIdx.x * 64;
  const int tid = threadIdx.x, tx = tid & 15, ty = tid >> 4;
  const float* Xb = X + ((size_t)b * NN + i0) * FF;
  const float* Yb = Y + ((size_t)b * MM + j0) * FF;
#pragma unroll
  for (int rep = 0; rep < 4; ++rep) {
    int row = rep * 16 + ty;
    float4 vx = *(const float4*)(Xb + row * FF + tx * 4);
    *(float4*)&xs[row][tx * 4] = vx;
    float4 vy = *(const float4*)(Yb + row * FF + tx * 4);
    ysT[tx * 4 + 0][row] = vy.x;
    ysT[tx * 4 + 1][row] = vy.y;
    ysT[tx * 4 + 2][row] = vy.z;
    ysT[tx * 4 + 3][row] = vy.w;
  }
  __syncthreads();

  const int il0 = ty * 4, jl0 = tx * 4;
  float c[4][4] = {};
#pragma unroll
  for (int k = 0; k < FF; ++k) {
    float a0 = xs[il0 + 0][k], a1 = xs[il0 + 1][k], a2 = xs[il0 + 2][k], a3 = xs[il0 + 3][k];
    float4 bv = *(const float4*)&ysT[k][jl0];
    c[0][0] = fmaf(a0, bv.x, c[0][0]); c[0][1] = fmaf(a0, bv.y, c[0][1]);
    c[0][2] = fmaf(a0, bv.z, c[0][2]); c[0][3] = fmaf(a0, bv.w, c[0][3]);
    c[1][0] = fmaf(a1, bv.x, c[1][0]); c[1][1] = fmaf(a1, bv.y, c[1][1]);
    c[1][2] = fmaf(a1, bv.z, c[1][2]); c[1][3] = fmaf(a1, bv.w, c[1][3]);
    c[2][0] = fmaf(a2, bv.x, c[2][0]); c[2][1] = fmaf(a2, bv.y, c[2][1]);
    c[2][2] = fmaf(a2, bv.z, c[2][2]); c[2][3] = fmaf(a2, bv.w, c[2][3]);
    c[3][0] = fmaf(a3, bv.x, c[3][0]); c[3][1] = fmaf(a3, bv.y, c[3][1]);
    c[3][2] = fmaf(a3, bv.z, c[3][2]); c[3][3] = fmaf(a3, bv.w, c[3][3]);
  }

  float x2v[4], y2v[4];
#pragma unroll
  for (int p = 0; p < 4; ++p) x2v[p] = x2[b * NN + i0 + il0 + p];
#pragma unroll
  for (int q = 0; q < 4; ++q) y2v[q] = y2[b * MM + j0 + jl0 + q];
  __syncthreads();
#pragma unroll
  for (int p = 0; p < 4; ++p) {
    float4 r;
    r.x = sqrtf(fmaxf(x2v[p] + y2v[0] - 2.f * c[p][0], 0.f));
    r.y = sqrtf(fmaxf(x2v[p] + y2v[1] - 2.f * c[p][1], 0.f));
    r.z = sqrtf(fmaxf(x2v[p] + y2v[2] - 2.f * c[p][2], 0.f));
    r.w = sqrtf(fmaxf(x2v[p] + y2v[3] - 2.f * c[p][3], 0.f));
    *(float4*)&xs[il0 + p][jl0] = r;
  }
  __syncthreads();

  // stripe-major write-out (skew-2: t = j0/2 + cp + 2l)
  const int lt = tid & 15, cpp0 = tid >> 4;
  const int l0 = (i0 & 255) >> 2;
  char* bb = dist + (size_t)(b * NBANDS + (i0 >> 8)) * BANDBYTES;
#pragma unroll
  for (int u = 0; u < 4; ++u) {
    int cpp = cpp0 + u * 16;            // tile col 0..63
    int cp = cpp >> 1, par = cpp & 1;
    int l = l0 + lt;
    int t = (j0 >> 1) + cp + 2 * l;     // stripe index (skew-2)
    unsigned w0 = pk_bf16x2(xs[lt * 4 + 0][cpp], xs[lt * 4 + 1][cpp]);
    unsigned w1 = pk_bf16x2(xs[lt * 4 + 2][cpp], xs[lt * 4 + 3][cpp]);
    *(uint2*)(bb + (size_t)t * 1024 + l * 16 + par * 8) = make_uint2(w0, w1);
  }
}

// ---------------- DP: 8-band pipeline, skew-2, latency-hidden shfl ----------------
// Tick T, lane l, pair p=T-2l. Needs: nA,nB = neighbor (A3,B3)@pair p (its
// tick T-2; shfl issued at top of tick T-1 reading prevA3=@T-2... i.e. each
// tick issues the shfl for the NEXT tick -> full tick body covers DS latency),
// nBp = neighbor B3@pair p-1 (last tick's nB). Lane 0 takes ring values:
// ring slot = producer tick = pair + 126 (producer lane63 skew).

#define TICK(S, QV)                                                     \
  {                                                                     \
    float nAn = __shfl_up(prevA3, 1, 64);  /* -> next tick's nA */      \
    float nBn = __shfl_up(prevB3, 1, 64);                               \
    float rA = __shfl(rvx, (S), 64);                                    \
    float rB = __shfl(rvy, (S), 64);                                    \
    float upA = isl0 ? rA : nA;                                         \
    float upB = isl0 ? rB : nB;                                         \
    float dgA = isl0 ? topPrev : nBp;                                   \
    float dA0 = __uint_as_float((QV).x << 16);                          \
    float dA1 = __uint_as_float((QV).x & 0xFFFF0000u);                  \
    float dA2 = __uint_as_float((QV).y << 16);                          \
    float dA3 = __uint_as_float((QV).y & 0xFFFF0000u);                  \
    float dB0 = __uint_as_float((QV).z << 16);                          \
    float dB1 = __uint_as_float((QV).z & 0xFFFF0000u);                  \
    float dB2 = __uint_as_float((QV).w << 16);                          \
    float dB3 = __uint_as_float((QV).w & 0xFFFF0000u);                  \
    float A0 = dA0 + fminf(fminf(P0, dgA), upA);                        \
    float A1 = dA1 + fminf(fminf(P1, P0), A0);                          \
    float A2 = dA2 + fminf(fminf(P2, P1), A1);                          \
    float A3 = dA3 + fminf(fminf(P3, P2), A2);                          \
    float B0 = dB0 + fminf(fminf(A0, upA), upB);                        \
    float B1 = dB1 + fminf(fminf(A1, A0), B0);                          \
    float B2 = dB2 + fminf(fminf(A2, A1), B1);                          \
    float B3 = dB3 + fminf(fminf(A3, A2), B2);                          \
    P0 = B0; P1 = B1; P2 = B2; P3 = B3;                                 \
    prevA3 = A3; prevB3 = B3;                                           \
    nBp = nB; nA = nAn; nB = nBn;                                       \
    topPrev = rB;                                                       \
    pubA[S] = A3; pubB[S] = B3;                                         \
  }

#define LDA4(A, B, C, D, BASE)                                          \
  asm volatile("global_load_dwordx4 %0, %4, off\n\t"                    \
               "global_load_dwordx4 %1, %4, off offset:1024\n\t"        \
               "global_load_dwordx4 %2, %4, off offset:2048\n\t"        \
               "global_load_dwordx4 %3, %4, off offset:3072"            \
               : "=&v"(A), "=&v"(B), "=&v"(C), "=&v"(D)                 \
               : "v"(BASE)                                              \
               : "memory")

#define LOADQA(DST, CB)                                                 \
  {                                                                     \
    const char* qn_ = bandbase + ((size_t)(CB) << 14) + (lane << 4);    \
    LDA4(DST[0], DST[1], DST[2], DST[3], qn_);                          \
    LDA4(DST[4], DST[5], DST[6], DST[7], qn_ + 4096);                   \
    LDA4(DST[8], DST[9], DST[10], DST[11], qn_ + 8192);                 \
    LDA4(DST[12], DST[13], DST[14], DST[15], qn_ + 12288);              \
  }

// pinned ring prefetch for chunk CB: slots CB*16 + 126 + (lane&15)
#define RINGLOAD(RV, CB)                                                \
  {                                                                     \
    const char* rp_ = (const char*)ringIn +                             \
                      ((((size_t)(CB) << 4) + 126 + (lane & 15)) << 3); \
    asm volatile("global_load_dwordx2 %0, %1, off"                      \
                 : "=&v"(RV) : "v"(rp_) : "memory");                    \
  }

#define SPIN(TGT)                                                       \
  {                                                                     \
    int guard = 0;                                                      \
    while (__hip_atomic_load(flagIn, __ATOMIC_ACQUIRE,                  \
                             __HIP_MEMORY_SCOPE_AGENT) < (unsigned)(TGT)) { \
      __builtin_amdgcn_s_sleep(2);                                      \
      if (++guard > (1 << 26)) break;                                   \
    }                                                                   \
  }

#define PUBLISH(CP)                                                     \
  if (lane == 63) {                                                     \
    float4* rp = (float4*)(ringOut + ((size_t)(CP) << 4));              \
    rp[0] = make_float4(pubA[0], pubB[0], pubA[1], pubB[1]);            \
    rp[1] = make_float4(pubA[2], pubB[2], pubA[3], pubB[3]);            \
    rp[2] = make_float4(pubA[4], pubB[4], pubA[5], pubB[5]);            \
    rp[3] = make_float4(pubA[6], pubB[6], pubA[7], pubB[7]);            \
    rp[4] = make_float4(pubA[8], pubB[8], pubA[9], pubB[9]);            \
    rp[5] = make_float4(pubA[10], pubB[10], pubA[11], pubB[11]);        \
    rp[6] = make_float4(pubA[12], pubB[12], pubA[13], pubB[13]);        \
    rp[7] = make_float4(pubA[14], pubB[14], pubA[15], pubB[15]);        \
    __hip_atomic_store(flagOut, (unsigned)((CP) + 1), __ATOMIC_RELEASE, \
                       __HIP_MEMORY_SCOPE_AGENT);                       \
  }

// Chunk: publish(c-1) [release fence drains prior loads: tick-covered] ->
// take prefetched ring values -> spin+issue pinned ring prefetch for c+1 ->
// drain(free) -> issue 16 pinned dist loads for c+1 -> 16 ticks.
#define CHUNK(CUR, NXT, CC)                                             \
  do {                                                                  \
    const int c_ = (CC);                                                \
    if (c_ > 0) PUBLISH(c_ - 1);                                        \
    float rvx = rvn.x, rvy = rvn.y;  /* pairs c*16..+15 (lane&15 dup) */ \
    rvn.x = INF; rvn.y = INF;                                           \
    asm volatile("s_waitcnt vmcnt(0)" ::: "memory");                    \
    __builtin_amdgcn_sched_barrier(0);                                  \
    LOADQA(NXT, (c_ < 71 ? c_ + 1 : 71));                               \
    if (g && c_ + 1 <= 63) {                                            \
      SPIN(c_ + 10);                                                    \
      RINGLOAD(rvn, c_ + 1);                                            \
    }                                                                   \
    TICK(0, CUR[0])  TICK(1, CUR[1])  TICK(2, CUR[2])  TICK(3, CUR[3])  \
    TICK(4, CUR[4])  TICK(5, CUR[5])  TICK(6, CUR[6])  TICK(7, CUR[7])  \
    TICK(8, CUR[8])  TICK(9, CUR[9])  TICK(10, CUR[10]) TICK(11, CUR[11]) \
    TICK(12, CUR[12]) TICK(13, CUR[13]) TICK(14, CUR[14]) TICK(15, CUR[15]) \
  } while (0)

__global__ __launch_bounds__(64, 1) void dp_k(const char* __restrict__ dist,
                                              float2* __restrict__ ring,
                                              unsigned* __restrict__ flags,
                                              float* __restrict__ out) {
  const int bid = blockIdx.x;     // = b*8 + g
  const int g = bid & 7, b = bid >> 3;
  const int lane = threadIdx.x;
  const bool isl0 = (lane == 0);
  const char* bandbase = dist + (size_t)bid * BANDBYTES;
  float2* ringOut = (float2*)(ring + (size_t)bid * RING_SLOTS);
  const char* ringIn = (const char*)(ring + (size_t)(bid - 1) * RING_SLOTS);
  unsigned* flagOut = flags + bid;
  const unsigned* flagIn = flags + (bid - 1);                    // used iff g>0

  float P0 = INF, P1 = INF, P2 = INF, P3 = INF;
  float prevA3 = INF, prevB3 = INF;
  float nA = INF, nB = INF, nBp = INF;
  float topPrev = (g == 0 && lane == 0) ? 0.f : INF;  // cell (0,0) diag
  float pubA[16], pubB[16];
  uint4 qa[16], qb[16];
  f32x2 rvn; rvn.x = INF; rvn.y = INF;

  LOADQA(qa, 0);
  if (g) {
    SPIN(9);            // chunk-0 ring data: producer ticks 126..141
    RINGLOAD(rvn, 0);
  }
  asm volatile("s_waitcnt vmcnt(0)" ::: "memory");  // one-time prologue drain
  __builtin_amdgcn_sched_barrier(0);

  for (int cc = 0; cc < 72; cc += 2) {
    CHUNK(qa, qb, cc);
    CHUNK(qb, qa, cc + 1);
  }
  PUBLISH(71);  // final flag = 72

  // D[2047][2047]: band 7, lane 63, pair 1023 -> tick 1149 = chunk 71 step 5
  if (g == 7 && lane == 63) out[b] = pubB[5];
}

extern "C" void kernel_launch(void* const* d_in, const int* in_sizes, int n_in,
                              void* d_out, int out_size, void* d_ws, size_t ws_size,
                              hipStream_t stream) {
  const float* X = (const float*)d_in[0];
  const float* Y = (const float*)d_in[1];
  float* out = (float*)d_out;

  float* x2 = (float*)d_ws;                       // 64KB
  float* y2 = x2 + BB * NN;                       // 64KB
  char* dist = (char*)d_ws + 131072;              // 75.5MB stripe-major bf16
  float2* ring = (float2*)(dist + DIST_BYTES);    // 590KB
  unsigned* flags = (unsigned*)((char*)ring + RING_BYTES);  // 256B

  norms_k<<<dim3((BB * NN + 255) / 256), dim3(256), 0, stream>>>(X, x2, BB * NN);
  norms_k<<<dim3((BB * MM + 255) / 256), dim3(256), 0, stream>>>(Y, y2, BB * MM);
  fill_k<<<dim3(2048), dim3(256), 0, stream>>>((uint4*)dist, (int)(DIST_BYTES / 16));
  hipMemsetAsync(flags, 0, BB * NBANDS * sizeof(unsigned), stream);

  dist_k<<<dim3(MM / 64, NN / 64, BB), dim3(256), 0, stream>>>(X, Y, x2, y2, dist);
  dp_k<<<dim3(BB * NBANDS), dim3(64), 0, stream>>>(dist, ring, flags, out);
}

// Round 13
// 320.480 us; speedup vs baseline: 1.6105x; 1.6105x over previous
//
#include <hip/hip_runtime.h>
#include <hip/hip_bf16.h>

#define BB 8
#define NN 2048
#define MM 2048
#define FF 64
#define INF __builtin_inff()

// ---- pipelined-DP geometry (skew-2, verified r11 modulo output index) ----
// 8 bands of 256 rows per batch; one 64-lane WG per band; lane l owns rows
// 4l..4l+3. Tick T: lane l processes pair p = T - 2l (cols 2p, 2p+1).
// Stripe t (1KB): lane l's 16B = rows 4l..4l+3 of cols 2(t-2l), 2(t-2l)+1.
#define STRIPES 1152                 // 1024 pairs + 126 skew + pad
#define BANDBYTES (STRIPES * 1024)
#define NBANDS 8
#define DIST_BYTES ((size_t)BB * NBANDS * BANDBYTES)
#define RING_SLOTS 1152              // float2 per producer tick
#define RING_BYTES ((size_t)BB * NBANDS * RING_SLOTS * 8)
#define SENT 0x7FC00000u             // NaN sentinel: never produced by the DP

typedef __hip_bfloat16 bf16;
typedef float f32x2 __attribute__((ext_vector_type(2)));
typedef float f32x4 __attribute__((ext_vector_type(4)));  // asm-safe vec4

__device__ __forceinline__ unsigned pk_bf16x2(float a, float b) {
  union { __hip_bfloat162 h; unsigned u; } cv;
  cv.h.x = __float2bfloat16(a);
  cv.h.y = __float2bfloat16(b);
  return cv.u;
}

__device__ __forceinline__ f32x4 mkf4(float a, float b, float c, float d) {
  f32x4 v; v.x = a; v.y = b; v.z = c; v.w = d; return v;
}

// ---------------- row norms ----------------
__global__ void norms_k(const float* __restrict__ a, float* __restrict__ o, int rows) {
  int r = blockIdx.x * 256 + threadIdx.x;
  if (r >= rows) return;
  const float4* p = (const float4*)(a + (size_t)r * FF);
  float s = 0.f;
#pragma unroll
  for (int q = 0; q < FF / 4; ++q) {
    float4 v = p[q];
    s = fmaf(v.x, v.x, fmaf(v.y, v.y, fmaf(v.z, v.z, fmaf(v.w, v.w, s))));
  }
  o[r] = s;
}

// fills (re-run every launch: ring sentinels + dist INF-pad)
__global__ void fill_k(uint4* __restrict__ p, int n4, unsigned pat) {
  int i = blockIdx.x * 256 + threadIdx.x;
  const int stride = gridDim.x * 256;
  const uint4 v = make_uint4(pat, pat, pat, pat);
  for (; i < n4; i += stride) p[i] = v;
}

// ---------------- dist tile kernel (byte-identical to r11; verified) ----------
__global__ __launch_bounds__(256) void dist_k(const float* __restrict__ X,
                                              const float* __restrict__ Y,
                                              const float* __restrict__ x2,
                                              const float* __restrict__ y2,
                                              char* __restrict__ dist) {
  __shared__ float xs[64][68];
  __shared__ float ysT[64][68];
  const int b = blockIdx.z, i0 = blockIdx.y * 64, j0 = blockIdx.x * 64;
  const int tid = threadIdx.x, tx = tid & 15, ty = tid >> 4;
  const float* Xb = X + ((size_t)b * NN + i0) * FF;
  const float* Yb = Y + ((size_t)b * MM + j0) * FF;
#pragma unroll
  for (int rep = 0; rep < 4; ++rep) {
    int row = rep * 16 + ty;
    float4 vx = *(const float4*)(Xb + row * FF + tx * 4);
    *(float4*)&xs[row][tx * 4] = vx;
    float4 vy = *(const float4*)(Yb + row * FF + tx * 4);
    ysT[tx * 4 + 0][row] = vy.x;
    ysT[tx * 4 + 1][row] = vy.y;
    ysT[tx * 4 + 2][row] = vy.z;
    ysT[tx * 4 + 3][row] = vy.w;
  }
  __syncthreads();

  const int il0 = ty * 4, jl0 = tx * 4;
  float c[4][4] = {};
#pragma unroll
  for (int k = 0; k < FF; ++k) {
    float a0 = xs[il0 + 0][k], a1 = xs[il0 + 1][k], a2 = xs[il0 + 2][k], a3 = xs[il0 + 3][k];
    float4 bv = *(const float4*)&ysT[k][jl0];
    c[0][0] = fmaf(a0, bv.x, c[0][0]); c[0][1] = fmaf(a0, bv.y, c[0][1]);
    c[0][2] = fmaf(a0, bv.z, c[0][2]); c[0][3] = fmaf(a0, bv.w, c[0][3]);
    c[1][0] = fmaf(a1, bv.x, c[1][0]); c[1][1] = fmaf(a1, bv.y, c[1][1]);
    c[1][2] = fmaf(a1, bv.z, c[1][2]); c[1][3] = fmaf(a1, bv.w, c[1][3]);
    c[2][0] = fmaf(a2, bv.x, c[2][0]); c[2][1] = fmaf(a2, bv.y, c[2][1]);
    c[2][2] = fmaf(a2, bv.z, c[2][2]); c[2][3] = fmaf(a2, bv.w, c[2][3]);
    c[3][0] = fmaf(a3, bv.x, c[3][0]); c[3][1] = fmaf(a3, bv.y, c[3][1]);
    c[3][2] = fmaf(a3, bv.z, c[3][2]); c[3][3] = fmaf(a3, bv.w, c[3][3]);
  }

  float x2v[4], y2v[4];
#pragma unroll
  for (int p = 0; p < 4; ++p) x2v[p] = x2[b * NN + i0 + il0 + p];
#pragma unroll
  for (int q = 0; q < 4; ++q) y2v[q] = y2[b * MM + j0 + jl0 + q];
  __syncthreads();
#pragma unroll
  for (int p = 0; p < 4; ++p) {
    float4 r;
    r.x = sqrtf(fmaxf(x2v[p] + y2v[0] - 2.f * c[p][0], 0.f));
    r.y = sqrtf(fmaxf(x2v[p] + y2v[1] - 2.f * c[p][1], 0.f));
    r.z = sqrtf(fmaxf(x2v[p] + y2v[2] - 2.f * c[p][2], 0.f));
    r.w = sqrtf(fmaxf(x2v[p] + y2v[3] - 2.f * c[p][3], 0.f));
    *(float4*)&xs[il0 + p][jl0] = r;
  }
  __syncthreads();

  // stripe-major write-out (skew-2: t = j0/2 + cp + 2l)
  const int lt = tid & 15, cpp0 = tid >> 4;
  const int l0 = (i0 & 255) >> 2;
  char* bb = dist + (size_t)(b * NBANDS + (i0 >> 8)) * BANDBYTES;
#pragma unroll
  for (int u = 0; u < 4; ++u) {
    int cpp = cpp0 + u * 16;            // tile col 0..63
    int cp = cpp >> 1, par = cpp & 1;
    int l = l0 + lt;
    int t = (j0 >> 1) + cp + 2 * l;     // stripe index (skew-2)
    unsigned w0 = pk_bf16x2(xs[lt * 4 + 0][cpp], xs[lt * 4 + 1][cpp]);
    unsigned w1 = pk_bf16x2(xs[lt * 4 + 2][cpp], xs[lt * 4 + 3][cpp]);
    *(uint2*)(bb + (size_t)t * 1024 + l * 16 + par * 8) = make_uint2(w0, w1);
  }
}

// ---------------- DP: 8-band pipeline, sentinel ring (no flags/fences) --------
// ROUND-12: compile fix only (float4 struct -> f32x4 ext_vector for asm
// operands). Theory unchanged from r12: sentinel ring deletes per-chunk
// acquire/release round trips; sched_barrier(0) pins TICKs after the issue
// block so loads keep a full chunk of cover and qa/qb stay resident.

#define TICK(S, QV)                                                     \
  {                                                                     \
    float nAn = __shfl_up(prevA3, 1, 64);  /* -> next tick's nA */      \
    float nBn = __shfl_up(prevB3, 1, 64);                               \
    float rA = __shfl(rvx, (S), 64);                                    \
    float rB = __shfl(rvy, (S), 64);                                    \
    float upA = isl0 ? rA : nA;                                         \
    float upB = isl0 ? rB : nB;                                         \
    float dgA = isl0 ? topPrev : nBp;                                   \
    float dA0 = __uint_as_float((QV).x << 16);                          \
    float dA1 = __uint_as_float((QV).x & 0xFFFF0000u);                  \
    float dA2 = __uint_as_float((QV).y << 16);                          \
    float dA3 = __uint_as_float((QV).y & 0xFFFF0000u);                  \
    float dB0 = __uint_as_float((QV).z << 16);                          \
    float dB1 = __uint_as_float((QV).z & 0xFFFF0000u);                  \
    float dB2 = __uint_as_float((QV).w << 16);                          \
    float dB3 = __uint_as_float((QV).w & 0xFFFF0000u);                  \
    float A0 = dA0 + fminf(fminf(P0, dgA), upA);                        \
    float A1 = dA1 + fminf(fminf(P1, P0), A0);                          \
    float A2 = dA2 + fminf(fminf(P2, P1), A1);                          \
    float A3 = dA3 + fminf(fminf(P3, P2), A2);                          \
    float B0 = dB0 + fminf(fminf(A0, upA), upB);                        \
    float B1 = dB1 + fminf(fminf(A1, A0), B0);                          \
    float B2 = dB2 + fminf(fminf(A2, A1), B1);                          \
    float B3 = dB3 + fminf(fminf(A3, A2), B2);                          \
    P0 = B0; P1 = B1; P2 = B2; P3 = B3;                                 \
    prevA3 = A3; prevB3 = B3;                                           \
    nBp = nB; nA = nAn; nB = nBn;                                       \
    topPrev = rB;                                                       \
    pubA[S] = A3; pubB[S] = B3;                                         \
  }

#define LDA4(A, B, C, D, BASE)                                          \
  asm volatile("global_load_dwordx4 %0, %4, off\n\t"                    \
               "global_load_dwordx4 %1, %4, off offset:1024\n\t"        \
               "global_load_dwordx4 %2, %4, off offset:2048\n\t"        \
               "global_load_dwordx4 %3, %4, off offset:3072"            \
               : "=&v"(A), "=&v"(B), "=&v"(C), "=&v"(D)                 \
               : "v"(BASE)                                              \
               : "memory")

#define LOADQA(DST, CB)                                                 \
  {                                                                     \
    const char* qn_ = bandbase + ((size_t)(CB) << 14) + (lane << 4);    \
    LDA4(DST[0], DST[1], DST[2], DST[3], qn_);                          \
    LDA4(DST[4], DST[5], DST[6], DST[7], qn_ + 4096);                   \
    LDA4(DST[8], DST[9], DST[10], DST[11], qn_ + 8192);                 \
    LDA4(DST[12], DST[13], DST[14], DST[15], qn_ + 12288);              \
  }

#define RINGADDR(CB) (ringIn + ((((size_t)(CB) << 4) + 126 + (lane & 15)) << 3))

// pinned, L2-bypassing (sc0 sc1) ring prefetch for chunk CB
#define RINGLOAD(RV, CB)                                                \
  asm volatile("global_load_dwordx2 %0, %1, off sc0 sc1"                \
               : "=&v"(RV) : "v"(RINGADDR(CB)) : "memory")

// readiness = register compare vs sentinel; slow re-poll only at pipeline fill
#define VERIFY(RV, CB)                                                  \
  if (g && (CB) <= 63) {                                                \
    while (__float_as_uint((RV).x) == SENT) {                           \
      __builtin_amdgcn_s_sleep(4);                                      \
      asm volatile("global_load_dwordx2 %0, %1, off sc0 sc1\n\t"        \
                   "s_waitcnt vmcnt(0)"                                 \
                   : "=&v"(RV) : "v"(RINGADDR(CB)) : "memory");         \
    }                                                                   \
  }

// publish chunk CP: 8 write-through dwordx4 stores (land at L3 for consumers)
#define PUBLISH(CP)                                                     \
  if (lane == 63) {                                                     \
    char* rp_ = (char*)ringOut + ((size_t)(CP) << 7);                   \
    f32x4 f0 = mkf4(pubA[0], pubB[0], pubA[1], pubB[1]);                \
    f32x4 f1 = mkf4(pubA[2], pubB[2], pubA[3], pubB[3]);                \
    f32x4 f2 = mkf4(pubA[4], pubB[4], pubA[5], pubB[5]);                \
    f32x4 f3 = mkf4(pubA[6], pubB[6], pubA[7], pubB[7]);                \
    f32x4 f4 = mkf4(pubA[8], pubB[8], pubA[9], pubB[9]);                \
    f32x4 f5 = mkf4(pubA[10], pubB[10], pubA[11], pubB[11]);            \
    f32x4 f6 = mkf4(pubA[12], pubB[12], pubA[13], pubB[13]);            \
    f32x4 f7 = mkf4(pubA[14], pubB[14], pubA[15], pubB[15]);            \
    asm volatile(                                                       \
        "global_store_dwordx4 %8, %0, off sc0 sc1\n\t"                  \
        "global_store_dwordx4 %8, %1, off offset:16 sc0 sc1\n\t"        \
        "global_store_dwordx4 %8, %2, off offset:32 sc0 sc1\n\t"        \
        "global_store_dwordx4 %8, %3, off offset:48 sc0 sc1\n\t"        \
        "global_store_dwordx4 %8, %4, off offset:64 sc0 sc1\n\t"        \
        "global_store_dwordx4 %8, %5, off offset:80 sc0 sc1\n\t"        \
        "global_store_dwordx4 %8, %6, off offset:96 sc0 sc1\n\t"        \
        "global_store_dwordx4 %8, %7, off offset:112 sc0 sc1"           \
        :: "v"(f0), "v"(f1), "v"(f2), "v"(f3), "v"(f4), "v"(f5),        \
           "v"(f6), "v"(f7), "v"(rp_)                                   \
        : "memory");                                                    \
  }

// Chunk: drain (all ops 1 chunk old) -> sentinel check (register) ->
// issue ring+dist loads for c+1 -> publish(c-1) -> pinned ticks.
#define CHUNK(CUR, NXT, RVC, RVN, CC)                                   \
  do {                                                                  \
    const int c_ = (CC);                                                \
    asm volatile("s_waitcnt vmcnt(0)" ::: "memory");                    \
    __builtin_amdgcn_sched_barrier(0);                                  \
    VERIFY(RVC, c_);                                                    \
    float rvx = RVC.x, rvy = RVC.y;                                     \
    if (g && c_ + 1 <= 63) { RINGLOAD(RVN, c_ + 1); }                   \
    else { RVN.x = INF; RVN.y = INF; }                                  \
    LOADQA(NXT, (c_ < 71 ? c_ + 1 : 71));                               \
    if (c_ > 0) PUBLISH(c_ - 1);                                        \
    __builtin_amdgcn_sched_barrier(0);                                  \
    TICK(0, CUR[0])  TICK(1, CUR[1])  TICK(2, CUR[2])  TICK(3, CUR[3])  \
    TICK(4, CUR[4])  TICK(5, CUR[5])  TICK(6, CUR[6])  TICK(7, CUR[7])  \
    TICK(8, CUR[8])  TICK(9, CUR[9])  TICK(10, CUR[10]) TICK(11, CUR[11]) \
    TICK(12, CUR[12]) TICK(13, CUR[13]) TICK(14, CUR[14]) TICK(15, CUR[15]) \
  } while (0)

__global__ __launch_bounds__(64, 1) void dp_k(const char* __restrict__ dist,
                                              float2* __restrict__ ring,
                                              float* __restrict__ out) {
  const int bid = blockIdx.x;     // = b*8 + g
  const int g = bid & 7, b = bid >> 3;
  const int lane = threadIdx.x;
  const bool isl0 = (lane == 0);
  const char* bandbase = dist + (size_t)bid * BANDBYTES;
  float2* ringOut = ring + (size_t)bid * RING_SLOTS;
  const char* ringIn = (const char*)(ring + (size_t)(bid - 1) * RING_SLOTS);

  float P0 = INF, P1 = INF, P2 = INF, P3 = INF;
  float prevA3 = INF, prevB3 = INF;
  float nA = INF, nB = INF, nBp = INF;
  float topPrev = (g == 0 && lane == 0) ? 0.f : INF;  // cell (0,0) diag
  float pubA[16], pubB[16];
  uint4 qa[16], qb[16];
  f32x2 rva, rvb;
  rva.x = INF; rva.y = INF; rvb.x = INF; rvb.y = INF;

  LOADQA(qa, 0);
  if (g) RINGLOAD(rva, 0);   // drained + verified at chunk-0 top

  for (int cc = 0; cc < 72; cc += 2) {
    CHUNK(qa, qb, rva, rvb, cc);
    CHUNK(qb, qa, rvb, rva, cc + 1);
  }
  PUBLISH(71);

  // D[2047][2047]: lane 63 pair 1023 -> tick 1149 = chunk 71, step 13
  if (g == 7 && lane == 63) out[b] = pubB[13];
}

extern "C" void kernel_launch(void* const* d_in, const int* in_sizes, int n_in,
                              void* d_out, int out_size, void* d_ws, size_t ws_size,
                              hipStream_t stream) {
  const float* X = (const float*)d_in[0];
  const float* Y = (const float*)d_in[1];
  float* out = (float*)d_out;

  float* x2 = (float*)d_ws;                       // 64KB
  float* y2 = x2 + BB * NN;                       // 64KB
  char* dist = (char*)d_ws + 131072;              // 75.5MB stripe-major bf16
  float2* ring = (float2*)(dist + DIST_BYTES);    // 590KB

  norms_k<<<dim3((BB * NN + 255) / 256), dim3(256), 0, stream>>>(X, x2, BB * NN);
  norms_k<<<dim3((BB * MM + 255) / 256), dim3(256), 0, stream>>>(Y, y2, BB * MM);
  fill_k<<<dim3(2048), dim3(256), 0, stream>>>((uint4*)dist, (int)(DIST_BYTES / 16), 0x7F7F7F7Fu);
  fill_k<<<dim3(144), dim3(256), 0, stream>>>((uint4*)ring, (int)(RING_BYTES / 16), SENT);

  dist_k<<<dim3(MM / 64, NN / 64, BB), dim3(256), 0, stream>>>(X, Y, x2, y2, dist);
  dp_k<<<dim3(BB * NBANDS), dim3(64), 0, stream>>>(dist, ring, out);
}

// Round 16
// 286.536 us; speedup vs baseline: 1.8013x; 1.1185x over previous
//
#include <hip/hip_runtime.h>
#include <hip/hip_bf16.h>

#define BB 8
#define NN 2048
#define MM 2048
#define FF 64
#define INF __builtin_inff()

// ---- pipelined-DP geometry (skew-2; r13-verified) ----
#define STRIPES 1152
#define BANDBYTES (STRIPES * 1024)
#define NBANDS 8
#define DIST_BYTES ((size_t)BB * NBANDS * BANDBYTES)
#define RING_SLOTS 1152
#define RING_BYTES ((size_t)BB * NBANDS * RING_SLOTS * 8)
#define SENT 0x7FC00000u

typedef __hip_bfloat16 bf16;
typedef float f32x2 __attribute__((ext_vector_type(2)));
typedef float f32x4 __attribute__((ext_vector_type(4)));

__device__ __forceinline__ unsigned pk_bf16x2(float a, float b) {
  union { __hip_bfloat162 h; unsigned u; } cv;
  cv.h.x = __float2bfloat16(a);
  cv.h.y = __float2bfloat16(b);
  return cv.u;
}
__device__ __forceinline__ f32x4 mkf4(float a, float b, float c, float d) {
  f32x4 v; v.x = a; v.y = b; v.z = c; v.w = d; return v;
}

// ---------------- row norms ----------------
__global__ void norms_k(const float* __restrict__ a, float* __restrict__ o, int rows) {
  int r = blockIdx.x * 256 + threadIdx.x;
  if (r >= rows) return;
  const float4* p = (const float4*)(a + (size_t)r * FF);
  float s = 0.f;
#pragma unroll
  for (int q = 0; q < FF / 4; ++q) {
    float4 v = p[q];
    s = fmaf(v.x, v.x, fmaf(v.y, v.y, fmaf(v.z, v.z, fmaf(v.w, v.w, s))));
  }
  o[r] = s;
}

// ring sentinel fill
__global__ void fill_k(uint4* __restrict__ p, int n4, unsigned pat) {
  int i = blockIdx.x * 256 + threadIdx.x;
  const int stride = gridDim.x * 256;
  const uint4 v = make_uint4(pat, pat, pat, pat);
  for (; i < n4; i += stride) p[i] = v;
}

// dist edge-stripe fill: unwritten slots {t<2l or t>1023+2l} are a subset of
// stripes {t<126 or t>=1024}; fill those fully, dist_k overwrites valid parts.
__global__ void fill2_k(char* __restrict__ dist) {
  int i = blockIdx.x * 256 + threadIdx.x;
  int band = i / 16256, rem = i - band * 16256;
  int stripe = rem >> 6, word = rem & 63;
  int t = stripe < 126 ? stripe : 1024 + (stripe - 126);
  uint4* p = (uint4*)(dist + (size_t)band * BANDBYTES + (size_t)t * 1024 + word * 16);
  *p = make_uint4(0x7F7F7F7Fu, 0x7F7F7F7Fu, 0x7F7F7F7Fu, 0x7F7F7F7Fu);
}

// ---------------- dist tile kernel (byte-identical to r13; verified) ----------
__global__ __launch_bounds__(256) void dist_k(const float* __restrict__ X,
                                              const float* __restrict__ Y,
                                              const float* __restrict__ x2,
                                              const float* __restrict__ y2,
                                              char* __restrict__ dist) {
  __shared__ float xs[64][68];
  __shared__ float ysT[64][68];
  const int b = blockIdx.z, i0 = blockIdx.y * 64, j0 = blockIdx.x * 64;
  const int tid = threadIdx.x, tx = tid & 15, ty = tid >> 4;
  const float* Xb = X + ((size_t)b * NN + i0) * FF;
  const float* Yb = Y + ((size_t)b * MM + j0) * FF;
#pragma unroll
  for (int rep = 0; rep < 4; ++rep) {
    int row = rep * 16 + ty;
    float4 vx = *(const float4*)(Xb + row * FF + tx * 4);
    *(float4*)&xs[row][tx * 4] = vx;
    float4 vy = *(const float4*)(Yb + row * FF + tx * 4);
    ysT[tx * 4 + 0][row] = vy.x;
    ysT[tx * 4 + 1][row] = vy.y;
    ysT[tx * 4 + 2][row] = vy.z;
    ysT[tx * 4 + 3][row] = vy.w;
  }
  __syncthreads();

  const int il0 = ty * 4, jl0 = tx * 4;
  float c[4][4] = {};
#pragma unroll
  for (int k = 0; k < FF; ++k) {
    float a0 = xs[il0 + 0][k], a1 = xs[il0 + 1][k], a2 = xs[il0 + 2][k], a3 = xs[il0 + 3][k];
    float4 bv = *(const float4*)&ysT[k][jl0];
    c[0][0] = fmaf(a0, bv.x, c[0][0]); c[0][1] = fmaf(a0, bv.y, c[0][1]);
    c[0][2] = fmaf(a0, bv.z, c[0][2]); c[0][3] = fmaf(a0, bv.w, c[0][3]);
    c[1][0] = fmaf(a1, bv.x, c[1][0]); c[1][1] = fmaf(a1, bv.y, c[1][1]);
    c[1][2] = fmaf(a1, bv.z, c[1][2]); c[1][3] = fmaf(a1, bv.w, c[1][3]);
    c[2][0] = fmaf(a2, bv.x, c[2][0]); c[2][1] = fmaf(a2, bv.y, c[2][1]);
    c[2][2] = fmaf(a2, bv.z, c[2][2]); c[2][3] = fmaf(a2, bv.w, c[2][3]);
    c[3][0] = fmaf(a3, bv.x, c[3][0]); c[3][1] = fmaf(a3, bv.y, c[3][1]);
    c[3][2] = fmaf(a3, bv.z, c[3][2]); c[3][3] = fmaf(a3, bv.w, c[3][3]);
  }

  float x2v[4], y2v[4];
#pragma unroll
  for (int p = 0; p < 4; ++p) x2v[p] = x2[b * NN + i0 + il0 + p];
#pragma unroll
  for (int q = 0; q < 4; ++q) y2v[q] = y2[b * MM + j0 + jl0 + q];
  __syncthreads();
#pragma unroll
  for (int p = 0; p < 4; ++p) {
    float4 r;
    r.x = sqrtf(fmaxf(x2v[p] + y2v[0] - 2.f * c[p][0], 0.f));
    r.y = sqrtf(fmaxf(x2v[p] + y2v[1] - 2.f * c[p][1], 0.f));
    r.z = sqrtf(fmaxf(x2v[p] + y2v[2] - 2.f * c[p][2], 0.f));
    r.w = sqrtf(fmaxf(x2v[p] + y2v[3] - 2.f * c[p][3], 0.f));
    *(float4*)&xs[il0 + p][jl0] = r;
  }
  __syncthreads();

  // stripe-major write-out (skew-2: t = j0/2 + cp + 2l)
  const int lt = tid & 15, cpp0 = tid >> 4;
  const int l0 = (i0 & 255) >> 2;
  char* bb = dist + (size_t)(b * NBANDS + (i0 >> 8)) * BANDBYTES;
#pragma unroll
  for (int u = 0; u < 4; ++u) {
    int cpp = cpp0 + u * 16;
    int cp = cpp >> 1, par = cpp & 1;
    int l = l0 + lt;
    int t = (j0 >> 1) + cp + 2 * l;
    unsigned w0 = pk_bf16x2(xs[lt * 4 + 0][cpp], xs[lt * 4 + 1][cpp]);
    unsigned w1 = pk_bf16x2(xs[lt * 4 + 2][cpp], xs[lt * 4 + 3][cpp]);
    *(uint2*)(bb + (size_t)t * 1024 + l * 16 + par * 8) = make_uint2(w0, w1);
  }
}

// ---------------- DP: 8-band pipeline; pipelined broadcasts; lean registers ---
// ROUND-15 POST-MORTEM: r14's uniform ring regs (rva/rvb = 64 VGPR) pushed
// live asm-pinned state to ~245+ regs -> allocator spilled asm-written regs
// (spill stores can't know the VGPR is written by an in-flight asm load) ->
// garbage. FIX: r13's per-lane f32x2 ring (2+2 regs) + the tick's broadcast
// shfls issued ONE TICK AHEAD (rAc/rBc <- rAn/rBn rotation), seeding tick 0
// at the chunk top under the issue block. All DS ops consumed next-tick.

#define TICK(S, QV, DONEXT)                                             \
  {                                                                     \
    float nAn = __shfl_up(prevA3, 1, 64);                               \
    float nBn = __shfl_up(prevB3, 1, 64);                               \
    float rAn = 0.f, rBn = 0.f;                                         \
    if (DONEXT) {                                                       \
      rAn = __shfl(rvx, (S) + 1, 64);                                   \
      rBn = __shfl(rvy, (S) + 1, 64);                                   \
    }                                                                   \
    float upA = isl0 ? rAc : nA;                                        \
    float upB = isl0 ? rBc : nB;                                        \
    float dgA = isl0 ? topPrev : nBp;                                   \
    float dA0 = __uint_as_float((QV).x << 16);                          \
    float dA1 = __uint_as_float((QV).x & 0xFFFF0000u);                  \
    float dA2 = __uint_as_float((QV).y << 16);                          \
    float dA3 = __uint_as_float((QV).y & 0xFFFF0000u);                  \
    float dB0 = __uint_as_float((QV).z << 16);                          \
    float dB1 = __uint_as_float((QV).z & 0xFFFF0000u);                  \
    float dB2 = __uint_as_float((QV).w << 16);                          \
    float dB3 = __uint_as_float((QV).w & 0xFFFF0000u);                  \
    float A0 = dA0 + fminf(fminf(P0, dgA), upA);                        \
    float A1 = dA1 + fminf(fminf(P1, P0), A0);                          \
    float A2 = dA2 + fminf(fminf(P2, P1), A1);                          \
    float A3 = dA3 + fminf(fminf(P3, P2), A2);                          \
    float B0 = dB0 + fminf(fminf(A0, upA), upB);                        \
    float B1 = dB1 + fminf(fminf(A1, A0), B0);                          \
    float B2 = dB2 + fminf(fminf(A2, A1), B1);                          \
    float B3 = dB3 + fminf(fminf(A3, A2), B2);                          \
    P0 = B0; P1 = B1; P2 = B2; P3 = B3;                                 \
    prevA3 = A3; prevB3 = B3;                                           \
    nBp = nB; nA = nAn; nB = nBn;                                       \
    topPrev = rBc;                                                      \
    if (DONEXT) { rAc = rAn; rBc = rBn; }                               \
    pubA[S] = A3; pubB[S] = B3;                                         \
  }

#define LDA4(A, B, C, D, BASE)                                          \
  asm volatile("global_load_dwordx4 %0, %4, off\n\t"                    \
               "global_load_dwordx4 %1, %4, off offset:1024\n\t"        \
               "global_load_dwordx4 %2, %4, off offset:2048\n\t"        \
               "global_load_dwordx4 %3, %4, off offset:3072"            \
               : "=&v"(A), "=&v"(B), "=&v"(C), "=&v"(D)                 \
               : "v"(BASE)                                              \
               : "memory")

#define LOADQA(DST, CB)                                                 \
  {                                                                     \
    const char* qn_ = bandbase + ((size_t)(CB) << 14) + (lane << 4);    \
    LDA4(DST[0], DST[1], DST[2], DST[3], qn_);                          \
    LDA4(DST[4], DST[5], DST[6], DST[7], qn_ + 4096);                   \
    LDA4(DST[8], DST[9], DST[10], DST[11], qn_ + 8192);                 \
    LDA4(DST[12], DST[13], DST[14], DST[15], qn_ + 12288);              \
  }

#define RINGADDR(CB) (ringIn + ((((size_t)(CB) << 4) + 126 + (lane & 15)) << 3))

// per-lane ring prefetch for chunk CB (lane j -> producer tick CB*16+126+j&15)
#define RINGLOAD(RV, CB)                                                \
  asm volatile("global_load_dwordx2 %0, %1, off sc0 sc1"                \
               : "=&v"(RV) : "v"(RINGADDR(CB)) : "memory")

// readiness = register compare vs sentinel; slow re-poll only at pipeline fill
#define VERIFY(RV, CB)                                                  \
  if (g && (CB) <= 63) {                                                \
    while (__float_as_uint((RV).x) == SENT) {                           \
      __builtin_amdgcn_s_sleep(4);                                      \
      asm volatile("global_load_dwordx2 %0, %1, off sc0 sc1\n\t"        \
                   "s_waitcnt vmcnt(0)"                                 \
                   : "=&v"(RV) : "v"(RINGADDR(CB)) : "memory");         \
    }                                                                   \
  }

// publish chunk CP: 8 write-through dwordx4 stores (land at L3 for consumers)
#define PUBLISH(CP)                                                     \
  if (lane == 63) {                                                     \
    char* rp_ = (char*)ringOut + ((size_t)(CP) << 7);                   \
    f32x4 f0 = mkf4(pubA[0], pubB[0], pubA[1], pubB[1]);                \
    f32x4 f1 = mkf4(pubA[2], pubB[2], pubA[3], pubB[3]);                \
    f32x4 f2 = mkf4(pubA[4], pubB[4], pubA[5], pubB[5]);                \
    f32x4 f3 = mkf4(pubA[6], pubB[6], pubA[7], pubB[7]);                \
    f32x4 f4 = mkf4(pubA[8], pubB[8], pubA[9], pubB[9]);                \
    f32x4 f5 = mkf4(pubA[10], pubB[10], pubA[11], pubB[11]);            \
    f32x4 f6 = mkf4(pubA[12], pubB[12], pubA[13], pubB[13]);            \
    f32x4 f7 = mkf4(pubA[14], pubB[14], pubA[15], pubB[15]);            \
    asm volatile(                                                       \
        "global_store_dwordx4 %8, %0, off sc0 sc1\n\t"                  \
        "global_store_dwordx4 %8, %1, off offset:16 sc0 sc1\n\t"        \
        "global_store_dwordx4 %8, %2, off offset:32 sc0 sc1\n\t"        \
        "global_store_dwordx4 %8, %3, off offset:48 sc0 sc1\n\t"        \
        "global_store_dwordx4 %8, %4, off offset:64 sc0 sc1\n\t"        \
        "global_store_dwordx4 %8, %5, off offset:80 sc0 sc1\n\t"        \
        "global_store_dwordx4 %8, %6, off offset:96 sc0 sc1\n\t"        \
        "global_store_dwordx4 %8, %7, off offset:112 sc0 sc1"           \
        :: "v"(f0), "v"(f1), "v"(f2), "v"(f3), "v"(f4), "v"(f5),        \
           "v"(f6), "v"(f7), "v"(rp_)                                   \
        : "memory");                                                    \
  }

// Chunk: counted drain (vmcnt(0) at c_==1 -- chunk 0 issued no stores;
// vmcnt(8) otherwise -- FIFO tail = last publish's stores) -> sentinel verify
// -> seed tick-0 broadcasts -> issue ring+dist for c+1 -> publish(c-1) ->
// pinned ticks (broadcasts rotate one tick ahead).
#define CHUNK(CUR, NXT, RVC, RVN, CC)                                   \
  do {                                                                  \
    const int c_ = (CC);                                                \
    if (c_ == 1) { asm volatile("s_waitcnt vmcnt(0)" ::: "memory"); }   \
    else         { asm volatile("s_waitcnt vmcnt(8)" ::: "memory"); }   \
    __builtin_amdgcn_sched_barrier(0);                                  \
    VERIFY(RVC, c_);                                                    \
    float rvx = RVC.x, rvy = RVC.y;                                     \
    rAc = __shfl(rvx, 0, 64);                                           \
    rBc = __shfl(rvy, 0, 64);                                           \
    if (g && c_ + 1 <= 63) { RINGLOAD(RVN, c_ + 1); }                   \
    else { RVN.x = INF; RVN.y = INF; }                                  \
    LOADQA(NXT, (c_ < 71 ? c_ + 1 : 71));                               \
    if (c_ > 0) PUBLISH(c_ - 1);                                        \
    __builtin_amdgcn_sched_barrier(0);                                  \
    TICK(0, CUR[0], 1)   TICK(1, CUR[1], 1)   TICK(2, CUR[2], 1)        \
    TICK(3, CUR[3], 1)   TICK(4, CUR[4], 1)   TICK(5, CUR[5], 1)        \
    TICK(6, CUR[6], 1)   TICK(7, CUR[7], 1)   TICK(8, CUR[8], 1)        \
    TICK(9, CUR[9], 1)   TICK(10, CUR[10], 1) TICK(11, CUR[11], 1)      \
    TICK(12, CUR[12], 1) TICK(13, CUR[13], 1) TICK(14, CUR[14], 1)      \
    TICK(15, CUR[15], 0)                                                \
  } while (0)

__global__ __launch_bounds__(64, 1) void dp_k(const char* __restrict__ dist,
                                              float2* __restrict__ ring,
                                              float* __restrict__ out) {
  const int bid = blockIdx.x;     // = b*8 + g
  const int g = bid & 7, b = bid >> 3;
  const int lane = threadIdx.x;
  const bool isl0 = (lane == 0);
  const char* bandbase = dist + (size_t)bid * BANDBYTES;
  float2* ringOut = ring + (size_t)bid * RING_SLOTS;
  const char* ringIn = (const char*)(ring + (size_t)(bid - 1) * RING_SLOTS);

  float P0 = INF, P1 = INF, P2 = INF, P3 = INF;
  float prevA3 = INF, prevB3 = INF;
  float nA = INF, nB = INF, nBp = INF;
  float rAc = INF, rBc = INF;
  float topPrev = (g == 0 && lane == 0) ? 0.f : INF;  // cell (0,0) diag
  float pubA[16], pubB[16];
  uint4 qa[16], qb[16];
  f32x2 rva, rvb;
  rva.x = INF; rva.y = INF; rvb.x = INF; rvb.y = INF;

  LOADQA(qa, 0);
  if (g) { RINGLOAD(rva, 0); }
  asm volatile("s_waitcnt vmcnt(0)" ::: "memory");  // one-time prologue drain
  __builtin_amdgcn_sched_barrier(0);

  for (int cc = 0; cc < 72; cc += 2) {
    CHUNK(qa, qb, rva, rvb, cc);
    CHUNK(qb, qa, rvb, rva, cc + 1);
  }
  PUBLISH(71);

  // D[2047][2047]: lane 63 pair 1023 -> tick 1149 = chunk 71, step 13
  if (g == 7 && lane == 63) out[b] = pubB[13];
}

extern "C" void kernel_launch(void* const* d_in, const int* in_sizes, int n_in,
                              void* d_out, int out_size, void* d_ws, size_t ws_size,
                              hipStream_t stream) {
  const float* X = (const float*)d_in[0];
  const float* Y = (const float*)d_in[1];
  float* out = (float*)d_out;

  float* x2 = (float*)d_ws;                       // 64KB
  float* y2 = x2 + BB * NN;                       // 64KB
  char* dist = (char*)d_ws + 131072;              // 75.5MB stripe-major bf16
  float2* ring = (float2*)(dist + DIST_BYTES);    // 590KB

  norms_k<<<dim3((BB * NN + 255) / 256), dim3(256), 0, stream>>>(X, x2, BB * NN);
  norms_k<<<dim3((BB * MM + 255) / 256), dim3(256), 0, stream>>>(Y, y2, BB * MM);
  fill2_k<<<dim3(4064), dim3(256), 0, stream>>>(dist);  // edge stripes only
  fill_k<<<dim3(144), dim3(256), 0, stream>>>((uint4*)ring, (int)(RING_BYTES / 16), SENT);

  dist_k<<<dim3(MM / 64, NN / 64, BB), dim3(256), 0, stream>>>(X, Y, x2, y2, dist);
  dp_k<<<dim3(BB * NBANDS), dim3(64), 0, stream>>>(dist, ring, out);
}